// Round 1
// baseline (281.423 us; speedup 1.0000x reference)
//
#include <hip/hip_runtime.h>

// Problem constants
#define NN    65536       // H*W
#define NSUB  256         // n per block
#define NBLK  (NN/NSUB)   // 256 blocks per batch
#define WPAD  260         // x LDS row stride (pad 4 -> even bank spread for column b128 reads)

// workspace layout (float offsets)
#define OFF_W   0
#define SZ_W    (8*64*24)          // Weff[b][c][h*3+j]
#define OFF_CJ  (OFF_W + SZ_W)
#define SZ_CJ   (8*24)             // Cj[b][h*3+j]
#define OFF_PM  (OFF_CJ + SZ_CJ)
#define SZ_P    (8*NBLK*8)         // per (b,blk,h)
#define OFF_PL  (OFF_PM + SZ_P)
#define OFF_PSP (OFF_PL + SZ_P)    // [.. ][2]
#define OFF_PSX (OFF_PSP + 2*SZ_P) // [..][64]

#define SMEM1_FLOATS (64*WPAD + 8*NSUB + 128)
#define SMEM1_BYTES  (SMEM1_FLOATS*4)

// ---------------- K0: per-(b,h) effective weights ----------------
// w_j[b,h,c] = sum_hd q[b,h,hd]*M_j[hd]*Wk[h*32+hd, c],  M_0=bp, M_1=Wp[:,0], M_2=Wp[:,1]
// c_j[b,h]   = sum_hd q*M_j*bk
__global__ __launch_bounds__(64) void prep_kernel(
    const float* __restrict__ z,  const float* __restrict__ Wq, const float* __restrict__ bq,
    const float* __restrict__ Wk, const float* __restrict__ bk,
    const float* __restrict__ Wp, const float* __restrict__ bp,
    float* __restrict__ Weff, float* __restrict__ Cj)
{
  const int h = blockIdx.x, b = blockIdx.y, t = threadIdx.x;
  __shared__ float q[32];
  if (t < 32) {
    const int e = h*32 + t;
    float a = bq[e];
    const float* zr = z + b*64;
    const float* wr = Wq + e*64;
    #pragma unroll 8
    for (int c = 0; c < 64; ++c) a += zr[c]*wr[c];
    q[t] = a;
  }
  __syncthreads();
  {
    const int c = t;
    float w0 = 0.f, w1 = 0.f, w2 = 0.f;
    #pragma unroll 4
    for (int hd = 0; hd < 32; ++hd) {
      const float qk = q[hd] * Wk[(h*32+hd)*64 + c];
      w0 += qk * bp[hd];
      w1 += qk * Wp[hd*2+0];
      w2 += qk * Wp[hd*2+1];
    }
    float* o = Weff + (b*64 + c)*24 + h*3;
    o[0] = w0; o[1] = w1; o[2] = w2;
  }
  if (t < 3) {
    float s = 0.f;
    for (int hd = 0; hd < 32; ++hd) {
      const float m = (t == 0) ? bp[hd] : Wp[hd*2 + (t-1)];
      s += q[hd] * m * bk[h*32+hd];
    }
    Cj[b*24 + h*3 + t] = s;
  }
}

// ---------------- K1: fused logits + block-softmax partials + weighted-x ----------------
__global__ __launch_bounds__(256) void main_kernel(
    const float* __restrict__ x, const float* __restrict__ pos,
    const float* __restrict__ Weff, const float* __restrict__ Cj,
    float* __restrict__ Pm, float* __restrict__ Pl,
    float* __restrict__ Psp, float* __restrict__ Psx)
{
  extern __shared__ float sm[];
  float* xs  = sm;                 // [64][WPAD] fp32 x tile
  float* ps  = sm + 64*WPAD;       // [8][NSUB]  probs (block-max-shifted)
  float* red = ps + 8*NSUB;        // [128] reduction scratch
  const int t   = threadIdx.x;
  const int blk = blockIdx.x;
  const int b   = blockIdx.y;
  const int n0  = blk * NSUB;

  // ---- stage x[b, :, n0:n0+256] -> LDS (coalesced float4) ----
  {
    const float* xb = x + (size_t)b*64*NN + n0;
    #pragma unroll
    for (int r = 0; r < 16; ++r) {
      const int f  = t + r*256;         // float4 id in [0,4096)
      const int c  = f >> 6;
      const int p4 = (f & 63) << 2;
      const float4 v = *(const float4*)(xb + (size_t)c*NN + p4);
      *(float4*)(xs + c*WPAD + p4) = v;
    }
  }

  // uniform per-block params (compiler: s_load)
  float cj[24];
  #pragma unroll
  for (int k = 0; k < 24; ++k) cj[k] = Cj[b*24 + k];
  float px[8], py[8];
  #pragma unroll
  for (int h = 0; h < 8; ++h) { px[h] = pos[(b*8+h)*2 + 0]; py[h] = pos[(b*8+h)*2 + 1]; }

  __syncthreads();

  // ---- phase A: logits for n = n0 + t (one n per thread) ----
  float acc[24];
  #pragma unroll
  for (int k = 0; k < 24; ++k) acc[k] = cj[k];
  const float* wb = Weff + b*64*24;
  for (int c = 0; c < 64; ++c) {
    const float xv = xs[c*WPAD + t];    // 2-way bank alias: free
    const float* wr = wb + c*24;        // uniform -> s_load_dwordx8
    #pragma unroll
    for (int k = 0; k < 24; ++k) acc[k] += wr[k]*xv;
  }
  const int   n  = n0 + t;
  const float gx = (float)(n >> 8);     // pos_grid row (W=256)
  const float gy = (float)(n & 255);    // pos_grid col
  float lg[8];
  #pragma unroll
  for (int h = 0; h < 8; ++h) {
    const float rx = gx - px[h];
    const float ry = gy - py[h];
    lg[h] = (acc[h*3+0] + rx*acc[h*3+1] + ry*acc[h*3+2]) * 0.17677669529663687f; // /sqrt(32)
  }

  // ---- block max per head ----
  float mh[8];
  #pragma unroll
  for (int h = 0; h < 8; ++h) {
    float m = lg[h];
    #pragma unroll
    for (int off = 32; off >= 1; off >>= 1) m = fmaxf(m, __shfl_xor(m, off, 64));
    mh[h] = m;
  }
  const int wid = t >> 6, lid = t & 63;
  if (lid == 0) {
    #pragma unroll
    for (int h = 0; h < 8; ++h) red[h*4 + wid] = mh[h];
  }
  __syncthreads();

  float p[8], trip[24];
  #pragma unroll
  for (int h = 0; h < 8; ++h) {
    const float M = fmaxf(fmaxf(red[h*4+0], red[h*4+1]), fmaxf(red[h*4+2], red[h*4+3]));
    mh[h] = M;
    p[h]  = __expf(lg[h] - M);
    trip[h*3+0] = p[h];
    trip[h*3+1] = p[h]*gx;
    trip[h*3+2] = p[h]*gy;
  }
  // block sums: l, sum p*gx, sum p*gy per head
  #pragma unroll
  for (int k = 0; k < 24; ++k) {
    float s = trip[k];
    #pragma unroll
    for (int off = 32; off >= 1; off >>= 1) s += __shfl_xor(s, off, 64);
    trip[k] = s;
  }
  if (lid == 0) {
    #pragma unroll
    for (int k = 0; k < 24; ++k) red[32 + k*4 + wid] = trip[k];
  }
  // stash probs for phase-B transpose
  #pragma unroll
  for (int h = 0; h < 8; ++h) ps[h*NSUB + t] = p[h];
  __syncthreads();

  if (t < 8) {
    const int h = t;
    const int base = (b*NBLK + blk)*8 + h;
    Pm[base] = mh[h];
    Pl[base] = red[32+(h*3+0)*4+0] + red[32+(h*3+0)*4+1] + red[32+(h*3+0)*4+2] + red[32+(h*3+0)*4+3];
    Psp[base*2+0] = red[32+(h*3+1)*4+0] + red[32+(h*3+1)*4+1] + red[32+(h*3+1)*4+2] + red[32+(h*3+1)*4+3];
    Psp[base*2+1] = red[32+(h*3+2)*4+0] + red[32+(h*3+2)*4+1] + red[32+(h*3+2)*4+2] + red[32+(h*3+2)*4+3];
  }

  // ---- phase B: sx[h][c] = sum_n p[h][n]*x[c][n]  ([8,256]x[256,64] LDS GEMM) ----
  // wave w handles heads {w, w+4}; lane -> c. p reads broadcast; x reads even 8/bank.
  {
    const int c  = t & 63;
    const int h0 = t >> 6;
    const float* xr  = xs + c*WPAD;
    const float* pr0 = ps + h0*NSUB;
    const float* pr1 = ps + (h0+4)*NSUB;
    float a0 = 0.f, a1 = 0.f;
    #pragma unroll 4
    for (int nn = 0; nn < NSUB; nn += 4) {
      const float4 xv = *(const float4*)(xr  + nn);
      const float4 q0 = *(const float4*)(pr0 + nn);
      const float4 q1 = *(const float4*)(pr1 + nn);
      a0 += xv.x*q0.x + xv.y*q0.y + xv.z*q0.z + xv.w*q0.w;
      a1 += xv.x*q1.x + xv.y*q1.y + xv.z*q1.z + xv.w*q1.w;
    }
    const int pb = (b*NBLK + blk)*8;
    Psx[(pb + h0    )*64 + c] = a0;
    Psx[(pb + h0 + 4)*64 + c] = a1;
  }
}

// ---------------- K2: combine block partials, project values ----------------
__global__ __launch_bounds__(256) void finish_kernel(
    const float* __restrict__ Pm, const float* __restrict__ Pl,
    const float* __restrict__ Psp, const float* __restrict__ Psx,
    const float* __restrict__ Wv, const float* __restrict__ bv,
    float* __restrict__ out)
{
  const int h = blockIdx.x, b = blockIdx.y, t = threadIdx.x;
  __shared__ float al[256];
  __shared__ float red[16];
  __shared__ float sxl[256];
  __shared__ float SXs[64];
  const int wid = t >> 6, lid = t & 63;
  const int pbase = (b*NBLK + t)*8 + h;

  const float m_t = Pm[pbase];
  float mm = m_t;
  #pragma unroll
  for (int off = 32; off >= 1; off >>= 1) mm = fmaxf(mm, __shfl_xor(mm, off, 64));
  if (lid == 0) red[wid] = mm;
  __syncthreads();
  const float M = fmaxf(fmaxf(red[0], red[1]), fmaxf(red[2], red[3]));
  const float a = __expf(m_t - M);
  al[t] = a;
  float lt  = Pl[pbase] * a;
  float sxt = Psp[pbase*2+0] * a;
  float syt = Psp[pbase*2+1] * a;
  #pragma unroll
  for (int off = 32; off >= 1; off >>= 1) {
    lt  += __shfl_xor(lt,  off, 64);
    sxt += __shfl_xor(sxt, off, 64);
    syt += __shfl_xor(syt, off, 64);
  }
  if (lid == 0) { red[4+wid] = lt; red[8+wid] = sxt; red[12+wid] = syt; }
  __syncthreads();
  const float L = red[4]+red[5]+red[6]+red[7];
  const float invL = 1.0f / L;

  // SX[c] = sum_blk Psx * alpha
  const int c = t & 63, g = t >> 6;
  float acc = 0.f;
  for (int k = 0; k < 64; ++k) {
    const int blk = g*64 + k;
    acc += Psx[((b*NBLK + blk)*8 + h)*64 + c] * al[blk];
  }
  sxl[g*64 + c] = acc;
  __syncthreads();
  if (t < 64) SXs[t] = (sxl[t] + sxl[64+t] + sxl[128+t] + sxl[192+t]) * invL;
  __syncthreads();

  // values[b,h,e] = Wv[e,:] . SX + bv[e]
  float v = bv[t];
  const float* wvr = Wv + t*64;
  #pragma unroll 8
  for (int c2 = 0; c2 < 64; ++c2) v += wvr[c2] * SXs[c2];
  out[(b*8+h)*256 + t] = v;

  if (t == 0) {
    const float SPx = red[8]+red[9]+red[10]+red[11];
    const float SPy = red[12]+red[13]+red[14]+red[15];
    out[16384 + (b*8+h)*2 + 0] = SPx * invL;
    out[16384 + (b*8+h)*2 + 1] = SPy * invL;
  }
}

extern "C" void kernel_launch(void* const* d_in, const int* in_sizes, int n_in,
                              void* d_out, int out_size, void* d_ws, size_t ws_size,
                              hipStream_t stream)
{
  const float* x   = (const float*)d_in[0];
  const float* z   = (const float*)d_in[1];
  const float* pos = (const float*)d_in[2];
  const float* Wq  = (const float*)d_in[3];
  const float* bq  = (const float*)d_in[4];
  const float* Wk  = (const float*)d_in[5];
  const float* bk  = (const float*)d_in[6];
  const float* Wv  = (const float*)d_in[7];
  const float* bv  = (const float*)d_in[8];
  const float* Wp  = (const float*)d_in[9];
  const float* bp  = (const float*)d_in[10];
  float* out = (float*)d_out;
  float* ws  = (float*)d_ws;

  float* Weff = ws + OFF_W;
  float* Cj   = ws + OFF_CJ;
  float* Pm   = ws + OFF_PM;
  float* Pl   = ws + OFF_PL;
  float* Psp  = ws + OFF_PSP;
  float* Psx  = ws + OFF_PSX;

  // 75264 B dynamic LDS (> 64 KB default) — opt in every call (idempotent, not a stream op)
  (void)hipFuncSetAttribute((const void*)main_kernel,
                            hipFuncAttributeMaxDynamicSharedMemorySize, SMEM1_BYTES);

  prep_kernel  <<<dim3(8,8),    64,  0,           stream>>>(z, Wq, bq, Wk, bk, Wp, bp, Weff, Cj);
  main_kernel  <<<dim3(NBLK,8), 256, SMEM1_BYTES, stream>>>(x, pos, Weff, Cj, Pm, Pl, Psp, Psx);
  finish_kernel<<<dim3(8,8),    256, 0,           stream>>>(Pm, Pl, Psp, Psx, Wv, bv, out);
}

// Round 2
// 264.749 us; speedup vs baseline: 1.0630x; 1.0630x over previous
//
#include <hip/hip_runtime.h>

// Problem constants
#define NN    65536       // H*W (H=W=256)
#define NSUB  256         // n per block
#define NBLK  (NN/NSUB)   // 256 blocks per batch
#define WPAD  260         // x LDS row stride: b32 column reads 2-way (free), b128 row reads at bank floor

// workspace layout (float offsets)
#define OFF_W   0
#define SZ_W    (8*64*24)          // Weff[b][c][h*3+j]
#define OFF_CJ  (OFF_W + SZ_W)
#define SZ_CJ   (8*24)             // Cj[b][h*3+j]
#define OFF_PM  (OFF_CJ + SZ_CJ)
#define SZ_P    (8*NBLK*8)         // per (b,blk,h)
#define OFF_PL  (OFF_PM + SZ_P)
#define OFF_PSP (OFF_PL + SZ_P)    // [..][2]
#define OFF_PSX (OFF_PSP + 2*SZ_P) // [..][64]

// LDS: xs[64][260] + ps[8][256] + wsw[1536] + red[64]  = 20288 floats = 81152 B (2 blocks/CU)
#define SMEM1_FLOATS (64*WPAD + 8*256 + 1536 + 64)
#define SMEM1_BYTES  (SMEM1_FLOATS*4)

// ---------------- K0: per-(b,h) effective weights ----------------
// w_j[b,h,c] = sum_hd q[b,h,hd]*M_j[hd]*Wk[h*32+hd, c],  M_0=bp, M_1=Wp[:,0], M_2=Wp[:,1]
// c_j[b,h]   = sum_hd q*M_j*bk
__global__ __launch_bounds__(64) void prep_kernel(
    const float* __restrict__ z,  const float* __restrict__ Wq, const float* __restrict__ bq,
    const float* __restrict__ Wk, const float* __restrict__ bk,
    const float* __restrict__ Wp, const float* __restrict__ bp,
    float* __restrict__ Weff, float* __restrict__ Cj)
{
  const int h = blockIdx.x, b = blockIdx.y, t = threadIdx.x;
  __shared__ float q[32];
  if (t < 32) {
    const int e = h*32 + t;
    float a = bq[e];
    const float* zr = z + b*64;
    const float* wr = Wq + e*64;
    #pragma unroll 8
    for (int c = 0; c < 64; ++c) a += zr[c]*wr[c];
    q[t] = a;
  }
  __syncthreads();
  {
    const int c = t;
    float w0 = 0.f, w1 = 0.f, w2 = 0.f;
    #pragma unroll 4
    for (int hd = 0; hd < 32; ++hd) {
      const float qk = q[hd] * Wk[(h*32+hd)*64 + c];
      w0 += qk * bp[hd];
      w1 += qk * Wp[hd*2+0];
      w2 += qk * Wp[hd*2+1];
    }
    float* o = Weff + (b*64 + c)*24 + h*3;
    o[0] = w0; o[1] = w1; o[2] = w2;
  }
  if (t < 3) {
    float s = 0.f;
    for (int hd = 0; hd < 32; ++hd) {
      const float m = (t == 0) ? bp[hd] : Wp[hd*2 + (t-1)];
      s += q[hd] * m * bk[h*32+hd];
    }
    Cj[b*24 + h*3 + t] = s;
  }
}

// ---------------- K1: fused logits + block-softmax partials + weighted-x ----------------
__global__ __launch_bounds__(256) void main_kernel(
    const float* __restrict__ x, const float* __restrict__ pos,
    const float* __restrict__ Weff, const float* __restrict__ Cj,
    float* __restrict__ Pm, float* __restrict__ Pl,
    float* __restrict__ Psp, float* __restrict__ Psx)
{
  extern __shared__ float sm[];
  float* xs  = sm;                 // [64][WPAD] fp32 x tile
  float* ps  = xs + 64*WPAD;       // [8][256]  probs (block-max-shifted)
  float* wsw = ps + 8*256;         // [1536] Weff[b] slice
  float* red = wsw + 1536;         // [64] reduction scratch
  const int t   = threadIdx.x;
  const int blk = blockIdx.x;
  const int b   = blockIdx.y;
  const int n0  = blk * NSUB;
  const int wid = t >> 6, lid = t & 63;

  // ---- stage x[b, :, n0:n0+256] -> LDS (coalesced float4) + Weff[b] slice ----
  {
    const float* xb = x + (size_t)b*64*NN + n0;
    #pragma unroll
    for (int r = 0; r < 16; ++r) {
      const int f  = t + r*256;         // float4 id in [0,4096)
      const int c  = f >> 6;
      const int p4 = (f & 63) << 2;
      const float4 v = *(const float4*)(xb + (size_t)c*NN + p4);
      *(float4*)(xs + c*WPAD + p4) = v;
    }
    const float* wsrc = Weff + b*1536;
    #pragma unroll
    for (int r = 0; r < 6; ++r) wsw[t + r*256] = wsrc[t + r*256];
  }

  // uniform per-block params (b, blk uniform -> scalar loads)
  float cj[24];
  #pragma unroll
  for (int k = 0; k < 24; ++k) cj[k] = Cj[b*24 + k];
  float rxh[8], py[8];
  #pragma unroll
  for (int h = 0; h < 8; ++h) {
    rxh[h] = (float)blk - pos[(b*8+h)*2 + 0];   // gx == n>>8 == blk for the whole block
    py[h]  = pos[(b*8+h)*2 + 1];
  }

  __syncthreads();

  // ---- phase A: logits for n = n0 + t. Pure-LDS loop: w broadcasts + x b32. ----
  float2 acc2[12];
  #pragma unroll
  for (int j = 0; j < 12; ++j) acc2[j] = make_float2(cj[2*j], cj[2*j+1]);
  #pragma unroll 2
  for (int c = 0; c < 64; ++c) {
    const float xv = xs[c*WPAD + t];                      // 2-way bank alias: free
    const float2* wr = (const float2*)(wsw + c*24);       // wave-uniform -> LDS broadcast b128s
    #pragma unroll
    for (int j = 0; j < 12; ++j) {
      acc2[j].x += wr[j].x * xv;                          // pairable -> v_pk_fma_f32
      acc2[j].y += wr[j].y * xv;
    }
  }
  const float* acc = (const float*)acc2;
  const float tyf = (float)t;                             // gy == n&255 == t
  float lg[8];
  #pragma unroll
  for (int h = 0; h < 8; ++h)
    lg[h] = (acc[h*3+0] + rxh[h]*acc[h*3+1] + (tyf - py[h])*acc[h*3+2]) * 0.17677669529663687f;

  // ---- block max per head ----
  float mh[8];
  #pragma unroll
  for (int h = 0; h < 8; ++h) {
    float m = lg[h];
    #pragma unroll
    for (int off = 32; off >= 1; off >>= 1) m = fmaxf(m, __shfl_xor(m, off, 64));
    mh[h] = m;
  }
  if (lid == 0) {
    #pragma unroll
    for (int h = 0; h < 8; ++h) red[h*4 + wid] = mh[h];
  }
  __syncthreads();

  #pragma unroll
  for (int h = 0; h < 8; ++h) {
    const float M = fmaxf(fmaxf(red[h*4+0], red[h*4+1]), fmaxf(red[h*4+2], red[h*4+3]));
    mh[h] = M;
    ps[h*256 + t] = __expf(lg[h] - M);
  }
  __syncthreads();

  // ---- per-head block sums: wave w handles heads {2w, 2w+1} over all 256 n ----
  {
    const int h0 = wid*2;
    const float4 pa = *(const float4*)(ps + h0*256 + 4*lid);
    const float4 pb = *(const float4*)(ps + (h0+1)*256 + 4*lid);
    const float j0 = (float)(4*lid);
    float s0a = pa.x + pa.y + pa.z + pa.w;
    float s1a = pa.x*j0 + pa.y*(j0+1.f) + pa.z*(j0+2.f) + pa.w*(j0+3.f);
    float s0b = pb.x + pb.y + pb.z + pb.w;
    float s1b = pb.x*j0 + pb.y*(j0+1.f) + pb.z*(j0+2.f) + pb.w*(j0+3.f);
    #pragma unroll
    for (int off = 32; off >= 1; off >>= 1) {
      s0a += __shfl_xor(s0a, off, 64);
      s1a += __shfl_xor(s1a, off, 64);
      s0b += __shfl_xor(s0b, off, 64);
      s1b += __shfl_xor(s1b, off, 64);
    }
    if (lid == 0) {
      const int base = (b*NBLK + blk)*8;
      const float blkf = (float)blk;
      Pm[base+h0]   = mh[h0];   Pl[base+h0]   = s0a;
      Psp[(base+h0)*2+0]   = blkf*s0a;  Psp[(base+h0)*2+1]   = s1a;
      Pm[base+h0+1] = mh[h0+1]; Pl[base+h0+1] = s0b;
      Psp[(base+h0+1)*2+0] = blkf*s0b;  Psp[(base+h0+1)*2+1] = s1b;
    }
  }

  // ---- phase B: sx[h][c] = sum_n p[h][n]*x[c][n] ----
  // wave w owns n-quarter [64w,64w+64), lane=c. x read ONCE per wave (b128 @ bank floor);
  // p reads are wave-uniform LDS broadcasts. 8 accumulators/thread.
  float aB[8];
  #pragma unroll
  for (int h = 0; h < 8; ++h) aB[h] = 0.f;
  {
    const int nq = wid*64;
    const float* xr = xs + lid*WPAD + nq;
    #pragma unroll 2
    for (int j = 0; j < 16; ++j) {
      const float4 xv = *(const float4*)(xr + 4*j);
      #pragma unroll
      for (int h = 0; h < 8; ++h) {
        const float4 pv = *(const float4*)(ps + h*256 + nq + 4*j);  // broadcast
        aB[h] += pv.x*xv.x + pv.y*xv.y + pv.z*xv.z + pv.w*xv.w;
      }
    }
  }
  __syncthreads();   // all xs/ps reads done; safe to reuse xs region
  {
    float* part = sm;                       // [4][8][64]
    #pragma unroll
    for (int h = 0; h < 8; ++h) part[(wid*8 + h)*64 + lid] = aB[h];
  }
  __syncthreads();
  {
    const int pb = (b*NBLK + blk)*8;
    #pragma unroll
    for (int r = 0; r < 2; ++r) {
      const int idx = t + 256*r;            // (h,c) flat, h=idx>>6, c=idx&63
      const float s = sm[idx] + sm[512+idx] + sm[1024+idx] + sm[1536+idx];
      Psx[(size_t)pb*64 + idx] = s;         // Psx[(pb+h)*64+c] == pb*64 + idx
    }
  }
}

// ---------------- K2: combine block partials, project values ----------------
__global__ __launch_bounds__(1024) void finish_kernel(
    const float* __restrict__ Pm, const float* __restrict__ Pl,
    const float* __restrict__ Psp, const float* __restrict__ Psx,
    const float* __restrict__ Wv, const float* __restrict__ bv,
    float* __restrict__ out)
{
  const int h = blockIdx.x, b = blockIdx.y, t = threadIdx.x;
  __shared__ float al[256];
  __shared__ float redm[32];
  __shared__ float sxl[1024];
  __shared__ float SXs[64];
  const int wid = t >> 6, lid = t & 63;

  float m_t = 0.f;
  if (t < 256) {
    m_t = Pm[(b*NBLK + t)*8 + h];
    float mm = m_t;
    #pragma unroll
    for (int off = 32; off >= 1; off >>= 1) mm = fmaxf(mm, __shfl_xor(mm, off, 64));
    if (lid == 0) redm[wid] = mm;
  }
  __syncthreads();
  const float M = fmaxf(fmaxf(redm[0], redm[1]), fmaxf(redm[2], redm[3]));
  if (t < 256) {
    const int pbase = (b*NBLK + t)*8 + h;
    const float a = __expf(m_t - M);
    al[t] = a;
    float lt  = Pl[pbase] * a;
    float sxt = Psp[pbase*2+0] * a;
    float syt = Psp[pbase*2+1] * a;
    #pragma unroll
    for (int off = 32; off >= 1; off >>= 1) {
      lt  += __shfl_xor(lt,  off, 64);
      sxt += __shfl_xor(sxt, off, 64);
      syt += __shfl_xor(syt, off, 64);
    }
    if (lid == 0) { redm[4+wid] = lt; redm[8+wid] = sxt; redm[12+wid] = syt; }
  }
  __syncthreads();
  const float L = redm[4]+redm[5]+redm[6]+redm[7];
  const float invL = 1.0f / L;

  // SX[c] = sum_blk Psx * alpha   (16 groups of 16 blks)
  {
    const int c = lid, g = wid;
    float acc = 0.f;
    #pragma unroll
    for (int k = 0; k < 16; ++k) {
      const int blk = g*16 + k;
      acc += Psx[((size_t)(b*NBLK + blk)*8 + h)*64 + c] * al[blk];
    }
    sxl[g*64 + c] = acc;
  }
  __syncthreads();
  if (t < 64) {
    float s = 0.f;
    #pragma unroll
    for (int g = 0; g < 16; ++g) s += sxl[g*64 + t];
    SXs[t] = s * invL;
  }
  __syncthreads();

  if (t < 256) {
    // values[b,h,e] = Wv[e,:] . SX + bv[e]
    float v = bv[t];
    const float* wvr = Wv + t*64;
    #pragma unroll 8
    for (int c2 = 0; c2 < 64; ++c2) v += wvr[c2] * SXs[c2];
    out[(b*8+h)*256 + t] = v;
  }
  if (t == 0) {
    const float SPx = redm[8]+redm[9]+redm[10]+redm[11];
    const float SPy = redm[12]+redm[13]+redm[14]+redm[15];
    out[16384 + (b*8+h)*2 + 0] = SPx * invL;
    out[16384 + (b*8+h)*2 + 1] = SPy * invL;
  }
}

extern "C" void kernel_launch(void* const* d_in, const int* in_sizes, int n_in,
                              void* d_out, int out_size, void* d_ws, size_t ws_size,
                              hipStream_t stream)
{
  const float* x   = (const float*)d_in[0];
  const float* z   = (const float*)d_in[1];
  const float* pos = (const float*)d_in[2];
  const float* Wq  = (const float*)d_in[3];
  const float* bq  = (const float*)d_in[4];
  const float* Wk  = (const float*)d_in[5];
  const float* bk  = (const float*)d_in[6];
  const float* Wv  = (const float*)d_in[7];
  const float* bv  = (const float*)d_in[8];
  const float* Wp  = (const float*)d_in[9];
  const float* bp  = (const float*)d_in[10];
  float* out = (float*)d_out;
  float* ws  = (float*)d_ws;

  float* Weff = ws + OFF_W;
  float* Cj   = ws + OFF_CJ;
  float* Pm   = ws + OFF_PM;
  float* Pl   = ws + OFF_PL;
  float* Psp  = ws + OFF_PSP;
  float* Psx  = ws + OFF_PSX;

  // 81152 B dynamic LDS (> 64 KB default) — opt in every call (host-side, graph-safe)
  (void)hipFuncSetAttribute((const void*)main_kernel,
                            hipFuncAttributeMaxDynamicSharedMemorySize, SMEM1_BYTES);

  prep_kernel  <<<dim3(8,8),    64,   0,           stream>>>(z, Wq, bq, Wk, bk, Wp, bp, Weff, Cj);
  main_kernel  <<<dim3(NBLK,8), 256,  SMEM1_BYTES, stream>>>(x, pos, Weff, Cj, Pm, Pl, Psp, Psx);
  finish_kernel<<<dim3(8,8),    1024, 0,           stream>>>(Pm, Pl, Psp, Psx, Wv, bv, out);
}